// Round 10
// baseline (527.311 us; speedup 1.0000x reference)
//
#include <hip/hip_runtime.h>
#include <cstdint>

// HistogramLoss via coarse empirical-CDF tables (LDS histograms) + per-input-bin linear
// map (AB table) + exact tail handling in small side arrays.
// matched[i] = sorted(target)[count(input <= input[i]) - 1], loss = mean((matched-input)^2)
//
// Round-9 finding: within-iteration load batching does NOT raise BW (146us, 950 GB/s,
// = R1/R3 exactly) -- loads are consumed in the iteration they issue, so each iteration
// still pays a full HBM latency; single-shot proved 1.9-2.3 TB/s but amplifies traffic.
// This revision: CROSS-ITERATION PREFETCH ROTATION on the traffic-clean loop structure.
// Iteration k issues loads for k+2 and consumes data loaded at k-2 (2 HBM latencies ago).
// The waitcnt before consumption targets long-arrived loads; stores (issued after those
// loads) never gate it. Addressing/store pattern identical to R3 (proven 66+66 MB clean).

#define NBINS    8192u              // uniform bins over [-16, 16)
#define HGX      512u               // hist blocks per histogram (8 iters/thread at n=2^24)
#define MGX      2048u              // match / collect blocks per stream (4 iters/thread)
#define KIN      2048u              // input tail rank cutoff (per side)
#define KTG      4096u              // target tail rank cutoff (per side)

__device__ __forceinline__ void bin_and_frac(float x, unsigned& b, float& frac) {
    float d = __builtin_fmaf(x, 256.0f, 4096.0f);      // (x+16)*256, one rounding, monotone
    d = fminf(fmaxf(d, 0.0f), 8191.999f);
    unsigned bb = (unsigned)d;
    b = bb;
    frac = d - (float)bb;
}

__device__ __forceinline__ void hist8(float4 A0, float4 A1, unsigned* h) {
    float xs[8] = {A0.x, A0.y, A0.z, A0.w, A1.x, A1.y, A1.z, A1.w};
    #pragma unroll
    for (int k = 0; k < 8; k++) {
        unsigned b; float f;
        bin_and_frac(xs[k], b, f);
        atomicAdd(&h[b], 1u);                // LDS atomic: lgkmcnt, never blocks vmem loads
    }
}

// LDS-private histogram; merge non-zero bins straight into global H.
// grid (HGX, 2): y==0 -> input -> H[0:NBINS], y==1 -> target -> H[NBINS:2*NBINS].
// Depth-2 prefetch rotation: consume data loaded 2 iterations ago.
__global__ __launch_bounds__(512, 8) void hist_kernel(const float* __restrict__ in,
                                                      const float* __restrict__ tg,
                                                      unsigned* __restrict__ H, unsigned n8) {
    __shared__ unsigned h[NBINS];
    for (unsigned i = threadIdx.x; i < NBINS; i += 512) h[i] = 0;
    __syncthreads();
    const float* xp = blockIdx.y ? tg : in;
    const float4* x4 = (const float4*)xp;
    unsigned* Hh = H + blockIdx.y * NBINS;
    unsigned stride = gridDim.x * 512;
    unsigned i0 = blockIdx.x * 512 + threadIdx.x;
    if (i0 < n8) {
        // prologue: batches for i0 and i0+stride
        unsigned iB = i0 + stride; unsigned iBc = (iB < n8) ? iB : i0;
        float4 p00 = x4[2 * i0], p01 = x4[2 * i0 + 1];
        float4 p10 = x4[2 * iBc], p11 = x4[2 * iBc + 1];
        for (unsigned i = i0; i < n8; i += stride) {
            unsigned nx = i + 2 * stride;
            unsigned nxc = (nx < n8) ? nx : i0;          // clamp: harmless dup load
            float4 q0 = x4[2 * nxc], q1 = x4[2 * nxc + 1];  // issue 2-ahead loads FIRST
            hist8(p00, p01, h);                          // consume 2-iterations-old data
            p00 = p10; p01 = p11; p10 = q0; p11 = q1;    // rotate
        }
    }
    __syncthreads();
    for (unsigned i = threadIdx.x; i < NBINS; i += 512) {
        unsigned v = h[i];
        if (v) atomicAdd(&Hh[i], v);        // spread-address atomics, fire-and-forget
    }
}

// Exclusive scan of one 8192-bin histogram per block -> C[NBINS+1]. grid = 2 blocks.
__global__ void scan_kernel(const unsigned* __restrict__ H, unsigned* __restrict__ C) {
    __shared__ unsigned s[1024];
    const unsigned* h = H + blockIdx.x * NBINS;
    unsigned* c = C + blockIdx.x * (NBINS + 1);
    unsigned base = threadIdx.x * 8;
    unsigned v[8]; unsigned own = 0;
    #pragma unroll
    for (int k = 0; k < 8; k++) { v[k] = h[base + k]; own += v[k]; }
    s[threadIdx.x] = own; __syncthreads();
    for (unsigned off = 1; off < 1024; off <<= 1) {
        unsigned t = (threadIdx.x >= off) ? s[threadIdx.x - off] : 0u;
        __syncthreads();
        s[threadIdx.x] += t;
        __syncthreads();
    }
    unsigned ex = s[threadIdx.x] - own;
    #pragma unroll
    for (int k = 0; k < 8; k++) { unsigned t = v[k]; c[base + k] = ex; ex += t; }
    if (threadIdx.x == 1023) c[NBINS] = s[1023];
}

// Per-input-bin linear map: matched(frac) = A[b] + B[b]*frac. Tail boundary bins for input
// (hdr[0:2]) and target (hdr[2:4]). All-zero init: bhi stored as (8192-b) under atomicMax,
// decoded as bhi = 8192 - hdr[odd]; hdr==0 -> bhi=8192 -> no upper tail (b<=8191 < 8192).
__global__ void buildAB_kernel(const unsigned* __restrict__ Cin, const unsigned* __restrict__ Ctg,
                               float2* __restrict__ AB, int* __restrict__ hdr, unsigned n) {
    unsigned b = blockIdx.x * blockDim.x + threadIdx.x;
    if (b >= NBINS) return;
    unsigned r0 = Cin[b], r1 = Cin[b + 1];
    if (r1 <= KIN) atomicMax(&hdr[0], (int)b);                 // input blo
    if (r0 >= n - KIN) atomicMax(&hdr[1], (int)(8192u - b));   // input bhi (encoded)
    unsigned t0 = Ctg[b], t1 = Ctg[b + 1];
    if (t1 <= KTG) atomicMax(&hdr[2], (int)b);                 // target blo (whole-bin, rank-closed)
    if (t0 >= n - KTG) atomicMax(&hdr[3], (int)(8192u - b));   // target bhi (encoded)
    if (r1 == r0) { AB[b] = make_float2(0.f, 0.f); return; }   // empty bin, never accessed for real
    const float w = 32.0f / (float)NBINS;
    float v[2];
    unsigned rr[2] = {r0, r1};
    #pragma unroll
    for (int k = 0; k < 2; k++) {
        unsigned r = rr[k]; if (r > n - 1) r = n - 1;
        unsigned lo = 0, hi = NBINS;                            // Ctg[lo] <= r < Ctg[hi]
        while (hi - lo > 1) { unsigned mid = (lo + hi) >> 1; if (Ctg[mid] <= r) lo = mid; else hi = mid; }
        unsigned c0 = Ctg[lo], c1 = Ctg[lo + 1];
        v[k] = -16.0f + (float)lo * w + w * ((float)(r - c0 + 1) / (float)(c1 - c0));
    }
    AB[b] = make_float2(v[0], v[1] - v[0]);
}

// Exact target order statistics into small arrays Tlo[r] (ranks [0,m)) and
// Thi[KTG-1-...] (top ranks). grid (4, 2): blockIdx.y = side, one j per thread.
__global__ void exact_target_kernel(const float* __restrict__ tg_lo, const float* __restrict__ tg_hi,
                                    const unsigned* __restrict__ ctrs,
                                    float* __restrict__ Tlo, float* __restrict__ Thi) {
    __shared__ __align__(16) float v[KTG];
    int side = blockIdx.y;
    const float* src = side ? tg_hi : tg_lo;
    unsigned m = ctrs[side ? 3 : 2];
    if (m > KTG) m = KTG;
    float sgn = side ? -1.f : 1.f;
    for (unsigned k = threadIdx.x; k < m; k += 1024) v[k] = sgn * src[k];
    __syncthreads();
    unsigned j = blockIdx.x * 1024 + threadIdx.x;
    if (j >= m) return;
    float y = v[j];
    unsigned lt = 0, le = 0;
    unsigned m4 = m & ~3u;
    for (unsigned k = 0; k < m4; k += 4) {
        float4 z = *(const float4*)&v[k];
        lt += (z.x < y) + (z.y < y) + (z.z < y) + (z.w < y);
        le += (z.x <= y) + (z.y <= y) + (z.z <= y) + (z.w <= y);
    }
    for (unsigned k = m4; k < m; k++) { lt += (v[k] < y); le += (v[k] <= y); }
    float yo = sgn * y;
    if (side) {
        for (unsigned idx = KTG - le; idx < KTG - lt; idx++) Thi[idx] = yo;  // global rank n-KTG+idx
    } else {
        for (unsigned r = lt; r < le; r++) Tlo[r] = yo;
    }
}

__device__ __forceinline__ void collect8(float4 A0, float4 A1, int blo, int bhi,
                                         float* __restrict__ tg_lo, float* __restrict__ tg_hi,
                                         unsigned* __restrict__ ctrs) {
    float xs[8] = {A0.x, A0.y, A0.z, A0.w, A1.x, A1.y, A1.z, A1.w};
    bool lo8[8], hi8[8]; bool any = false;
    #pragma unroll
    for (int k = 0; k < 8; k++) {
        unsigned b; float f;
        bin_and_frac(xs[k], b, f);
        lo8[k] = ((int)b <= blo);
        hi8[k] = ((int)b >= bhi);
        any = any || lo8[k] || hi8[k];
    }
    if (any) {
        #pragma unroll
        for (int k = 0; k < 8; k++) {
            if (lo8[k]) { unsigned p = atomicAdd(&ctrs[2], 1u); tg_lo[p] = xs[k]; }
            else if (hi8[k]) { unsigned p = atomicAdd(&ctrs[3], 1u); tg_hi[p] = xs[k]; }
        }
    }
}

__device__ __forceinline__ float match8(float4 A0, float4 A1, unsigned i,
                                        const float2* __restrict__ AB, int blo, int bhi,
                                        float* __restrict__ out,
                                        float* __restrict__ vlo, unsigned* __restrict__ ilo,
                                        float* __restrict__ vhi, unsigned* __restrict__ ihi,
                                        unsigned* __restrict__ ctrs) {
    float xs[8] = {A0.x, A0.y, A0.z, A0.w, A1.x, A1.y, A1.z, A1.w};
    unsigned b[8]; float fr[8];
    #pragma unroll
    for (int k = 0; k < 8; k++) bin_and_frac(xs[k], b[k], fr[k]);
    float2 ab[8];
    #pragma unroll
    for (int k = 0; k < 8; k++) ab[k] = AB[b[k]];        // 8 L2 gathers in flight
    float m[8]; bool tl[8]; bool any = false; float acc = 0.f;
    #pragma unroll
    for (int k = 0; k < 8; k++) {
        m[k] = __builtin_fmaf(ab[k].y, fr[k], ab[k].x);  // tail lanes: harmless placeholder
        tl[k] = ((int)b[k] <= blo) || ((int)b[k] >= bhi);
        any = any || tl[k];
        float d = tl[k] ? 0.f : (m[k] - xs[k]);
        acc = __builtin_fmaf(d, d, acc);
    }
    ((float4*)out)[2 * i]     = make_float4(m[0], m[1], m[2], m[3]);   // back-to-back covering stores
    ((float4*)out)[2 * i + 1] = make_float4(m[4], m[5], m[6], m[7]);
    if (any) {                                           // rare: tails overwritten later
        #pragma unroll
        for (int k = 0; k < 8; k++) {
            if (!tl[k]) continue;
            if ((int)b[k] <= blo) { unsigned p = atomicAdd(&ctrs[0], 1u); vlo[p] = xs[k]; ilo[p] = 8 * i + k; }
            else                  { unsigned p = atomicAdd(&ctrs[1], 1u); vhi[p] = xs[k]; ihi[p] = 8 * i + k; }
        }
    }
    return acc;
}

// Fused main pass. grid (MGX, 2), 256 threads. Depth-2 prefetch rotation on R3's
// proven-clean addressing (32B/lane, covering float4-pair stores).
//  y==0: interp-match (AB gathers from L2) + per-wave loss partials; collect input tails.
//  y==1: collect target tail elements via threshold-bin compares.
__global__ __launch_bounds__(256, 8) void matchcollect_kernel(
        const float* __restrict__ input, const float* __restrict__ target,
        const float2* __restrict__ AB, const int* __restrict__ hdr,
        float* __restrict__ vlo, unsigned* __restrict__ ilo,
        float* __restrict__ vhi, unsigned* __restrict__ ihi,
        float* __restrict__ tg_lo, float* __restrict__ tg_hi,
        unsigned* __restrict__ ctrs,
        float* __restrict__ out, float* __restrict__ bpart,
        unsigned n) {
    unsigned n8 = n >> 3;
    unsigned stride = gridDim.x * 256;
    unsigned i0 = blockIdx.x * 256 + threadIdx.x;

    if (blockIdx.y == 1) {
        int blo = hdr[2], bhi = 8192 - hdr[3];
        if (i0 < n8) {
            const float4* x4 = (const float4*)target;
            unsigned iB = i0 + stride; unsigned iBc = (iB < n8) ? iB : i0;
            float4 p00 = x4[2 * i0], p01 = x4[2 * i0 + 1];
            float4 p10 = x4[2 * iBc], p11 = x4[2 * iBc + 1];
            for (unsigned i = i0; i < n8; i += stride) {
                unsigned nx = i + 2 * stride;
                unsigned nxc = (nx < n8) ? nx : i0;          // clamp: harmless dup load
                float4 q0 = x4[2 * nxc], q1 = x4[2 * nxc + 1];
                collect8(p00, p01, blo, bhi, tg_lo, tg_hi, ctrs);
                p00 = p10; p01 = p11; p10 = q0; p11 = q1;
            }
        }
        return;
    }

    int blo = hdr[0], bhi = 8192 - hdr[1];
    float acc = 0.f;
    if (i0 < n8) {
        const float4* x4 = (const float4*)input;
        unsigned iB = i0 + stride; unsigned iBc = (iB < n8) ? iB : i0;
        float4 p00 = x4[2 * i0], p01 = x4[2 * i0 + 1];
        float4 p10 = x4[2 * iBc], p11 = x4[2 * iBc + 1];
        for (unsigned i = i0; i < n8; i += stride) {
            unsigned nx = i + 2 * stride;
            unsigned nxc = (nx < n8) ? nx : i0;              // clamp: harmless dup load
            float4 q0 = x4[2 * nxc], q1 = x4[2 * nxc + 1];   // issue 2-ahead loads FIRST
            acc += match8(p00, p01, i, AB, blo, bhi, out, vlo, ilo, vhi, ihi, ctrs);
            p00 = p10; p01 = p11; p10 = q0; p11 = q1;        // rotate
        }
    }
    #pragma unroll
    for (int off = 32; off > 0; off >>= 1) acc += __shfl_down(acc, off, 64);
    if ((threadIdx.x & 63) == 0)
        bpart[blockIdx.x * 4 + (threadIdx.x >> 6)] = acc;    // per-wave plain store
}

// Sum the per-wave partials -> *loss (plain store; exact_input atomicAdds after).
__global__ void loss_reduce_kernel(const float* __restrict__ bpart, float* __restrict__ loss,
                                   unsigned nb, unsigned n) {
    float s = 0.f;
    for (unsigned i = threadIdx.x; i < nb; i += 1024) s += bpart[i];
    #pragma unroll
    for (int off = 32; off > 0; off >>= 1) s += __shfl_down(s, off, 64);
    __shared__ float ws[16];
    int w = threadIdx.x >> 6;
    if ((threadIdx.x & 63) == 0) ws[w] = s;
    __syncthreads();
    if (threadIdx.x == 0) {
        float t = 0.f;
        #pragma unroll
        for (int k = 0; k < 16; k++) t += ws[k];
        *loss = t * (1.0f / (float)n);
    }
}

// Exact input tail matching. grid (2, 2): blockIdx.y = side, one j per thread.
// Runs LAST: overwrites the placeholder matched values at tail indices.
__global__ void exact_input_kernel(const float* __restrict__ in_lo_v, const unsigned* __restrict__ in_lo_i,
                                   const float* __restrict__ in_hi_v, const unsigned* __restrict__ in_hi_i,
                                   const unsigned* __restrict__ ctrs,
                                   const float* __restrict__ Tlo, const float* __restrict__ Thi,
                                   float* __restrict__ out, float* __restrict__ loss, unsigned n) {
    __shared__ __align__(16) float v[KIN];
    int side = blockIdx.y;
    const float* sv = side ? in_hi_v : in_lo_v;
    const unsigned* si = side ? in_hi_i : in_lo_i;
    unsigned m = ctrs[side ? 1 : 0];
    if (m > KIN) m = KIN;
    float sgn = side ? -1.f : 1.f;
    for (unsigned k = threadIdx.x; k < m; k += 1024) v[k] = sgn * sv[k];
    __syncthreads();
    unsigned j = blockIdx.x * 1024 + threadIdx.x;
    float d2 = 0.f;
    if (j < m) {
        float y = v[j];
        unsigned lt = 0, le = 0;
        unsigned m4 = m & ~3u;
        for (unsigned k = 0; k < m4; k += 4) {
            float4 z = *(const float4*)&v[k];
            lt += (z.x < y) + (z.y < y) + (z.z < y) + (z.w < y);
            le += (z.x <= y) + (z.y <= y) + (z.z <= y) + (z.w <= y);
        }
        for (unsigned k = m4; k < m; k++) { lt += (v[k] < y); le += (v[k] <= y); }
        // bottom: global rank = le-1 (< KIN <= KTG). top: global rank = n-1-lt -> Thi[KTG-1-lt].
        float mv = side ? Thi[KTG - 1 - lt] : Tlo[le - 1];
        float x = sgn * y;
        out[si[j]] = mv;
        float d = mv - x;
        d2 = d * d;
    }
    #pragma unroll
    for (int off = 32; off > 0; off >>= 1) d2 += __shfl_down(d2, off, 64);
    if ((threadIdx.x & 63) == 0 && d2 != 0.f)
        atomicAdd(loss, d2 * (1.0f / (float)n));
}

extern "C" void kernel_launch(void* const* d_in, const int* in_sizes, int n_in,
                              void* d_out, int out_size, void* d_ws, size_t ws_size,
                              hipStream_t stream) {
    const float* input  = (const float*)d_in[0];
    const float* target = (const float*)d_in[1];
    unsigned n = (unsigned)in_sizes[0];   // 16777216 = 2^24
    float* out  = (float*)d_out;
    float* loss = out + n;

    char* wsb = (char*)d_ws;
    unsigned* H    = (unsigned*)(wsb);                       // 2*NBINS*4 = 64 KB
    unsigned* Cin  = (unsigned*)(wsb + 64 * 1024);           // 2*(NBINS+1)*4
    unsigned* Ctg  = Cin + (NBINS + 1);
    float2*   AB   = (float2*)  (wsb + 160 * 1024);          // 64 KB
    char*     aux  = wsb + 224 * 1024;
    int*      hdr  = (int*)     (aux);                       // 16B [in_blo, enc_in_bhi, tg_blo, enc_tg_bhi]
    unsigned* ctrs = (unsigned*)(aux + 16);                  // 16B [in_lo, in_hi, tg_lo, tg_hi]
    float*    bpart= (float*)   (aux + 64);                  // MGX*4 floats (32 KB)
    char*     tails= aux + 64 + 65536 + 64;
    float*    in_lo_v = (float*)   (tails);
    unsigned* in_lo_i = (unsigned*)(tails + KIN * 4);
    float*    in_hi_v = (float*)   (tails + KIN * 8);
    unsigned* in_hi_i = (unsigned*)(tails + KIN * 12);
    float*    tg_lo   = (float*)   (tails + KIN * 16);
    float*    tg_hi   = (float*)   (tails + KIN * 16 + KTG * 4);
    float*    Tlo     = (float*)   (tails + KIN * 16 + KTG * 8);
    float*    Thi     = (float*)   (tails + KIN * 16 + KTG * 12);

    (void)hipMemsetAsync(H, 0, 2 * NBINS * 4, stream);
    (void)hipMemsetAsync(hdr, 0, 32, stream);                // hdr[4] + ctrs[4], all-zero init
    (void)hipMemsetAsync(loss, 0, 4, stream);

    unsigned n8 = n >> 3;

    hist_kernel<<<dim3(HGX, 2), 512, 0, stream>>>(input, target, H, n8);
    scan_kernel<<<2, 1024, 0, stream>>>(H, Cin);   // block 0 -> Cin, block 1 -> Ctg
    buildAB_kernel<<<NBINS / 256, 256, 0, stream>>>(Cin, Ctg, AB, hdr, n);

    matchcollect_kernel<<<dim3(MGX, 2), 256, 0, stream>>>(input, target, AB, hdr,
                                                          in_lo_v, in_lo_i, in_hi_v, in_hi_i,
                                                          tg_lo, tg_hi, ctrs, out, bpart, n);
    loss_reduce_kernel<<<1, 1024, 0, stream>>>(bpart, loss, MGX * 4, n);
    exact_target_kernel<<<dim3((KTG + 1023) / 1024, 2), 1024, 0, stream>>>(tg_lo, tg_hi, ctrs, Tlo, Thi);
    exact_input_kernel<<<dim3((KIN + 1023) / 1024, 2), 1024, 0, stream>>>(in_lo_v, in_lo_i, in_hi_v, in_hi_i,
                                                                          ctrs, Tlo, Thi, out, loss, n);
}

// Round 11
// 526.206 us; speedup vs baseline: 1.0021x; 1.0021x over previous
//
#include <hip/hip_runtime.h>
#include <cstdint>

// HistogramLoss via coarse empirical-CDF tables (LDS histograms) + per-input-bin linear
// map (AB table) + exact tail handling in small side arrays.
// matched[i] = sorted(target)[count(input <= input[i]) - 1], loss = mean((matched-input)^2)
//
// Ten-round law: duration = HBM_traffic / HBM_BW in every config. Clean-loop BW is pinned
// at ~950 GB/s; the suspect serializer is the per-CU vector-memory (TA) pipe, monopolized
// by 16.7M random 8B AB gathers (~50 distinct lines per 64-lane gather instruction, ~13x
// the line-probes of the streaming itself). R4's LDS test was confounded by 29% occupancy.
// This revision tests LDS-gathers AT FULL OCCUPANCY:
//   matchcollect: 1024-thread blocks, 64KB LDS AB table, launch_bounds(1024,2)
//   -> 2 blocks/CU (128KB LDS), 32 waves/CU (100%), VGPR 32 <= 64.
//   Streaming identical to R9 (proven clean 67+67MB): 32B/lane, depth-2 prefetch
//   rotation, covering float4-pair stores. Gathers now ds_read_b64 (off the VMEM pipe).

#define NBINS    8192u              // uniform bins over [-16, 16)
#define HGX      512u               // hist blocks per histogram
#define MGX      512u               // matchcollect blocks per stream (1024 thr each)
#define KIN      2048u              // input tail rank cutoff (per side)
#define KTG      4096u              // target tail rank cutoff (per side)

__device__ __forceinline__ void bin_and_frac(float x, unsigned& b, float& frac) {
    float d = __builtin_fmaf(x, 256.0f, 4096.0f);      // (x+16)*256, one rounding, monotone
    d = fminf(fmaxf(d, 0.0f), 8191.999f);
    unsigned bb = (unsigned)d;
    b = bb;
    frac = d - (float)bb;
}

__device__ __forceinline__ void hist8(float4 A0, float4 A1, unsigned* h) {
    float xs[8] = {A0.x, A0.y, A0.z, A0.w, A1.x, A1.y, A1.z, A1.w};
    #pragma unroll
    for (int k = 0; k < 8; k++) {
        unsigned b; float f;
        bin_and_frac(xs[k], b, f);
        atomicAdd(&h[b], 1u);                // LDS atomic: lgkmcnt, never blocks vmem loads
    }
}

// LDS-private histogram; merge non-zero bins straight into global H.
// grid (HGX, 2): y==0 -> input -> H[0:NBINS], y==1 -> target -> H[NBINS:2*NBINS].
// Depth-2 prefetch rotation: consume data loaded 2 iterations ago.
__global__ __launch_bounds__(512, 8) void hist_kernel(const float* __restrict__ in,
                                                      const float* __restrict__ tg,
                                                      unsigned* __restrict__ H, unsigned n8) {
    __shared__ unsigned h[NBINS];
    for (unsigned i = threadIdx.x; i < NBINS; i += 512) h[i] = 0;
    __syncthreads();
    const float* xp = blockIdx.y ? tg : in;
    const float4* x4 = (const float4*)xp;
    unsigned* Hh = H + blockIdx.y * NBINS;
    unsigned stride = gridDim.x * 512;
    unsigned i0 = blockIdx.x * 512 + threadIdx.x;
    if (i0 < n8) {
        unsigned iB = i0 + stride; unsigned iBc = (iB < n8) ? iB : i0;
        float4 p00 = x4[2 * i0], p01 = x4[2 * i0 + 1];
        float4 p10 = x4[2 * iBc], p11 = x4[2 * iBc + 1];
        for (unsigned i = i0; i < n8; i += stride) {
            unsigned nx = i + 2 * stride;
            unsigned nxc = (nx < n8) ? nx : i0;          // clamp: harmless dup load
            float4 q0 = x4[2 * nxc], q1 = x4[2 * nxc + 1];  // issue 2-ahead loads FIRST
            hist8(p00, p01, h);                          // consume 2-iterations-old data
            p00 = p10; p01 = p11; p10 = q0; p11 = q1;    // rotate
        }
    }
    __syncthreads();
    for (unsigned i = threadIdx.x; i < NBINS; i += 512) {
        unsigned v = h[i];
        if (v) atomicAdd(&Hh[i], v);        // spread-address atomics, fire-and-forget
    }
}

// Exclusive scan of one 8192-bin histogram per block -> C[NBINS+1]. grid = 2 blocks.
__global__ void scan_kernel(const unsigned* __restrict__ H, unsigned* __restrict__ C) {
    __shared__ unsigned s[1024];
    const unsigned* h = H + blockIdx.x * NBINS;
    unsigned* c = C + blockIdx.x * (NBINS + 1);
    unsigned base = threadIdx.x * 8;
    unsigned v[8]; unsigned own = 0;
    #pragma unroll
    for (int k = 0; k < 8; k++) { v[k] = h[base + k]; own += v[k]; }
    s[threadIdx.x] = own; __syncthreads();
    for (unsigned off = 1; off < 1024; off <<= 1) {
        unsigned t = (threadIdx.x >= off) ? s[threadIdx.x - off] : 0u;
        __syncthreads();
        s[threadIdx.x] += t;
        __syncthreads();
    }
    unsigned ex = s[threadIdx.x] - own;
    #pragma unroll
    for (int k = 0; k < 8; k++) { unsigned t = v[k]; c[base + k] = ex; ex += t; }
    if (threadIdx.x == 1023) c[NBINS] = s[1023];
}

// Per-input-bin linear map: matched(frac) = A[b] + B[b]*frac. Tail boundary bins for input
// (hdr[0:2]) and target (hdr[2:4]). All-zero init: bhi stored as (8192-b) under atomicMax,
// decoded as bhi = 8192 - hdr[odd]; hdr==0 -> bhi=8192 -> no upper tail (b<=8191 < 8192).
__global__ void buildAB_kernel(const unsigned* __restrict__ Cin, const unsigned* __restrict__ Ctg,
                               float2* __restrict__ AB, int* __restrict__ hdr, unsigned n) {
    unsigned b = blockIdx.x * blockDim.x + threadIdx.x;
    if (b >= NBINS) return;
    unsigned r0 = Cin[b], r1 = Cin[b + 1];
    if (r1 <= KIN) atomicMax(&hdr[0], (int)b);                 // input blo
    if (r0 >= n - KIN) atomicMax(&hdr[1], (int)(8192u - b));   // input bhi (encoded)
    unsigned t0 = Ctg[b], t1 = Ctg[b + 1];
    if (t1 <= KTG) atomicMax(&hdr[2], (int)b);                 // target blo (whole-bin, rank-closed)
    if (t0 >= n - KTG) atomicMax(&hdr[3], (int)(8192u - b));   // target bhi (encoded)
    if (r1 == r0) { AB[b] = make_float2(0.f, 0.f); return; }   // empty bin, never accessed for real
    const float w = 32.0f / (float)NBINS;
    float v[2];
    unsigned rr[2] = {r0, r1};
    #pragma unroll
    for (int k = 0; k < 2; k++) {
        unsigned r = rr[k]; if (r > n - 1) r = n - 1;
        unsigned lo = 0, hi = NBINS;                            // Ctg[lo] <= r < Ctg[hi]
        while (hi - lo > 1) { unsigned mid = (lo + hi) >> 1; if (Ctg[mid] <= r) lo = mid; else hi = mid; }
        unsigned c0 = Ctg[lo], c1 = Ctg[lo + 1];
        v[k] = -16.0f + (float)lo * w + w * ((float)(r - c0 + 1) / (float)(c1 - c0));
    }
    AB[b] = make_float2(v[0], v[1] - v[0]);
}

// Exact target order statistics into small arrays Tlo[r] (ranks [0,m)) and
// Thi[KTG-1-...] (top ranks). grid (4, 2): blockIdx.y = side, one j per thread.
__global__ void exact_target_kernel(const float* __restrict__ tg_lo, const float* __restrict__ tg_hi,
                                    const unsigned* __restrict__ ctrs,
                                    float* __restrict__ Tlo, float* __restrict__ Thi) {
    __shared__ __align__(16) float v[KTG];
    int side = blockIdx.y;
    const float* src = side ? tg_hi : tg_lo;
    unsigned m = ctrs[side ? 3 : 2];
    if (m > KTG) m = KTG;
    float sgn = side ? -1.f : 1.f;
    for (unsigned k = threadIdx.x; k < m; k += 1024) v[k] = sgn * src[k];
    __syncthreads();
    unsigned j = blockIdx.x * 1024 + threadIdx.x;
    if (j >= m) return;
    float y = v[j];
    unsigned lt = 0, le = 0;
    unsigned m4 = m & ~3u;
    for (unsigned k = 0; k < m4; k += 4) {
        float4 z = *(const float4*)&v[k];
        lt += (z.x < y) + (z.y < y) + (z.z < y) + (z.w < y);
        le += (z.x <= y) + (z.y <= y) + (z.z <= y) + (z.w <= y);
    }
    for (unsigned k = m4; k < m; k++) { lt += (v[k] < y); le += (v[k] <= y); }
    float yo = sgn * y;
    if (side) {
        for (unsigned idx = KTG - le; idx < KTG - lt; idx++) Thi[idx] = yo;  // global rank n-KTG+idx
    } else {
        for (unsigned r = lt; r < le; r++) Tlo[r] = yo;
    }
}

__device__ __forceinline__ void collect8(float4 A0, float4 A1, int blo, int bhi,
                                         float* __restrict__ tg_lo, float* __restrict__ tg_hi,
                                         unsigned* __restrict__ ctrs) {
    float xs[8] = {A0.x, A0.y, A0.z, A0.w, A1.x, A1.y, A1.z, A1.w};
    bool lo8[8], hi8[8]; bool any = false;
    #pragma unroll
    for (int k = 0; k < 8; k++) {
        unsigned b; float f;
        bin_and_frac(xs[k], b, f);
        lo8[k] = ((int)b <= blo);
        hi8[k] = ((int)b >= bhi);
        any = any || lo8[k] || hi8[k];
    }
    if (any) {
        #pragma unroll
        for (int k = 0; k < 8; k++) {
            if (lo8[k]) { unsigned p = atomicAdd(&ctrs[2], 1u); tg_lo[p] = xs[k]; }
            else if (hi8[k]) { unsigned p = atomicAdd(&ctrs[3], 1u); tg_hi[p] = xs[k]; }
        }
    }
}

// match8 with LDS AB table: gathers are ds_read_b64, off the vector-memory pipe.
__device__ __forceinline__ float match8(float4 A0, float4 A1, unsigned i,
                                        const float2* sAB, int blo, int bhi,
                                        float* __restrict__ out,
                                        float* __restrict__ vlo, unsigned* __restrict__ ilo,
                                        float* __restrict__ vhi, unsigned* __restrict__ ihi,
                                        unsigned* __restrict__ ctrs) {
    float xs[8] = {A0.x, A0.y, A0.z, A0.w, A1.x, A1.y, A1.z, A1.w};
    unsigned b[8]; float fr[8];
    #pragma unroll
    for (int k = 0; k < 8; k++) bin_and_frac(xs[k], b[k], fr[k]);
    float2 ab[8];
    #pragma unroll
    for (int k = 0; k < 8; k++) ab[k] = sAB[b[k]];       // 8 LDS gathers
    float m[8]; bool tl[8]; bool any = false; float acc = 0.f;
    #pragma unroll
    for (int k = 0; k < 8; k++) {
        m[k] = __builtin_fmaf(ab[k].y, fr[k], ab[k].x);  // tail lanes: harmless placeholder
        tl[k] = ((int)b[k] <= blo) || ((int)b[k] >= bhi);
        any = any || tl[k];
        float d = tl[k] ? 0.f : (m[k] - xs[k]);
        acc = __builtin_fmaf(d, d, acc);
    }
    ((float4*)out)[2 * i]     = make_float4(m[0], m[1], m[2], m[3]);   // back-to-back covering stores
    ((float4*)out)[2 * i + 1] = make_float4(m[4], m[5], m[6], m[7]);
    if (any) {                                           // rare: tails overwritten later
        #pragma unroll
        for (int k = 0; k < 8; k++) {
            if (!tl[k]) continue;
            if ((int)b[k] <= blo) { unsigned p = atomicAdd(&ctrs[0], 1u); vlo[p] = xs[k]; ilo[p] = 8 * i + k; }
            else                  { unsigned p = atomicAdd(&ctrs[1], 1u); vhi[p] = xs[k]; ihi[p] = 8 * i + k; }
        }
    }
    return acc;
}

// Fused main pass. grid (MGX, 2), 1024 threads. 64KB LDS AB table, 2 blocks/CU,
// 32 waves/CU (100% occupancy). Depth-2 prefetch rotation on R3/R9's clean addressing.
//  y==0: interp-match (AB gathers from LDS) + per-wave loss partials; collect input tails.
//  y==1: collect target tail elements via threshold-bin compares (LDS unused).
__global__ __launch_bounds__(1024, 2) void matchcollect_kernel(
        const float* __restrict__ input, const float* __restrict__ target,
        const float2* __restrict__ AB, const int* __restrict__ hdr,
        float* __restrict__ vlo, unsigned* __restrict__ ilo,
        float* __restrict__ vhi, unsigned* __restrict__ ihi,
        float* __restrict__ tg_lo, float* __restrict__ tg_hi,
        unsigned* __restrict__ ctrs,
        float* __restrict__ out, float* __restrict__ bpart,
        unsigned n) {
    __shared__ float2 sAB[NBINS];                        // 64 KB
    unsigned n8 = n >> 3;
    unsigned stride = gridDim.x * 1024;
    unsigned i0 = blockIdx.x * 1024 + threadIdx.x;

    if (blockIdx.y == 1) {
        int blo = hdr[2], bhi = 8192 - hdr[3];
        if (i0 < n8) {
            const float4* x4 = (const float4*)target;
            unsigned iB = i0 + stride; unsigned iBc = (iB < n8) ? iB : i0;
            float4 p00 = x4[2 * i0], p01 = x4[2 * i0 + 1];
            float4 p10 = x4[2 * iBc], p11 = x4[2 * iBc + 1];
            for (unsigned i = i0; i < n8; i += stride) {
                unsigned nx = i + 2 * stride;
                unsigned nxc = (nx < n8) ? nx : i0;          // clamp: harmless dup load
                float4 q0 = x4[2 * nxc], q1 = x4[2 * nxc + 1];
                collect8(p00, p01, blo, bhi, tg_lo, tg_hi, ctrs);
                p00 = p10; p01 = p11; p10 = q0; p11 = q1;
            }
        }
        return;
    }

    // stage AB into LDS: 8 coalesced rounds of 1024 x 8B
    for (unsigned j = threadIdx.x; j < NBINS; j += 1024) sAB[j] = AB[j];
    __syncthreads();

    int blo = hdr[0], bhi = 8192 - hdr[1];
    float acc = 0.f;
    if (i0 < n8) {
        const float4* x4 = (const float4*)input;
        unsigned iB = i0 + stride; unsigned iBc = (iB < n8) ? iB : i0;
        float4 p00 = x4[2 * i0], p01 = x4[2 * i0 + 1];
        float4 p10 = x4[2 * iBc], p11 = x4[2 * iBc + 1];
        for (unsigned i = i0; i < n8; i += stride) {
            unsigned nx = i + 2 * stride;
            unsigned nxc = (nx < n8) ? nx : i0;              // clamp: harmless dup load
            float4 q0 = x4[2 * nxc], q1 = x4[2 * nxc + 1];   // issue 2-ahead loads FIRST
            acc += match8(p00, p01, i, sAB, blo, bhi, out, vlo, ilo, vhi, ihi, ctrs);
            p00 = p10; p01 = p11; p10 = q0; p11 = q1;        // rotate
        }
    }
    #pragma unroll
    for (int off = 32; off > 0; off >>= 1) acc += __shfl_down(acc, off, 64);
    if ((threadIdx.x & 63) == 0)
        bpart[blockIdx.x * 16 + (threadIdx.x >> 6)] = acc;   // per-wave plain store
}

// Sum the per-wave partials -> *loss (plain store; exact_input atomicAdds after).
__global__ void loss_reduce_kernel(const float* __restrict__ bpart, float* __restrict__ loss,
                                   unsigned nb, unsigned n) {
    float s = 0.f;
    for (unsigned i = threadIdx.x; i < nb; i += 1024) s += bpart[i];
    #pragma unroll
    for (int off = 32; off > 0; off >>= 1) s += __shfl_down(s, off, 64);
    __shared__ float ws[16];
    int w = threadIdx.x >> 6;
    if ((threadIdx.x & 63) == 0) ws[w] = s;
    __syncthreads();
    if (threadIdx.x == 0) {
        float t = 0.f;
        #pragma unroll
        for (int k = 0; k < 16; k++) t += ws[k];
        *loss = t * (1.0f / (float)n);
    }
}

// Exact input tail matching. grid (2, 2): blockIdx.y = side, one j per thread.
// Runs LAST: overwrites the placeholder matched values at tail indices.
__global__ void exact_input_kernel(const float* __restrict__ in_lo_v, const unsigned* __restrict__ in_lo_i,
                                   const float* __restrict__ in_hi_v, const unsigned* __restrict__ in_hi_i,
                                   const unsigned* __restrict__ ctrs,
                                   const float* __restrict__ Tlo, const float* __restrict__ Thi,
                                   float* __restrict__ out, float* __restrict__ loss, unsigned n) {
    __shared__ __align__(16) float v[KIN];
    int side = blockIdx.y;
    const float* sv = side ? in_hi_v : in_lo_v;
    const unsigned* si = side ? in_hi_i : in_lo_i;
    unsigned m = ctrs[side ? 1 : 0];
    if (m > KIN) m = KIN;
    float sgn = side ? -1.f : 1.f;
    for (unsigned k = threadIdx.x; k < m; k += 1024) v[k] = sgn * sv[k];
    __syncthreads();
    unsigned j = blockIdx.x * 1024 + threadIdx.x;
    float d2 = 0.f;
    if (j < m) {
        float y = v[j];
        unsigned lt = 0, le = 0;
        unsigned m4 = m & ~3u;
        for (unsigned k = 0; k < m4; k += 4) {
            float4 z = *(const float4*)&v[k];
            lt += (z.x < y) + (z.y < y) + (z.z < y) + (z.w < y);
            le += (z.x <= y) + (z.y <= y) + (z.z <= y) + (z.w <= y);
        }
        for (unsigned k = m4; k < m; k++) { lt += (v[k] < y); le += (v[k] <= y); }
        // bottom: global rank = le-1 (< KIN <= KTG). top: global rank = n-1-lt -> Thi[KTG-1-lt].
        float mv = side ? Thi[KTG - 1 - lt] : Tlo[le - 1];
        float x = sgn * y;
        out[si[j]] = mv;
        float d = mv - x;
        d2 = d * d;
    }
    #pragma unroll
    for (int off = 32; off > 0; off >>= 1) d2 += __shfl_down(d2, off, 64);
    if ((threadIdx.x & 63) == 0 && d2 != 0.f)
        atomicAdd(loss, d2 * (1.0f / (float)n));
}

extern "C" void kernel_launch(void* const* d_in, const int* in_sizes, int n_in,
                              void* d_out, int out_size, void* d_ws, size_t ws_size,
                              hipStream_t stream) {
    const float* input  = (const float*)d_in[0];
    const float* target = (const float*)d_in[1];
    unsigned n = (unsigned)in_sizes[0];   // 16777216 = 2^24
    float* out  = (float*)d_out;
    float* loss = out + n;

    char* wsb = (char*)d_ws;
    unsigned* H    = (unsigned*)(wsb);                       // 2*NBINS*4 = 64 KB
    unsigned* Cin  = (unsigned*)(wsb + 64 * 1024);           // 2*(NBINS+1)*4
    unsigned* Ctg  = Cin + (NBINS + 1);
    float2*   AB   = (float2*)  (wsb + 160 * 1024);          // 64 KB
    char*     aux  = wsb + 224 * 1024;
    int*      hdr  = (int*)     (aux);                       // 16B [in_blo, enc_in_bhi, tg_blo, enc_tg_bhi]
    unsigned* ctrs = (unsigned*)(aux + 16);                  // 16B [in_lo, in_hi, tg_lo, tg_hi]
    float*    bpart= (float*)   (aux + 64);                  // MGX*16 floats (32 KB)
    char*     tails= aux + 64 + 65536 + 64;
    float*    in_lo_v = (float*)   (tails);
    unsigned* in_lo_i = (unsigned*)(tails + KIN * 4);
    float*    in_hi_v = (float*)   (tails + KIN * 8);
    unsigned* in_hi_i = (unsigned*)(tails + KIN * 12);
    float*    tg_lo   = (float*)   (tails + KIN * 16);
    float*    tg_hi   = (float*)   (tails + KIN * 16 + KTG * 4);
    float*    Tlo     = (float*)   (tails + KIN * 16 + KTG * 8);
    float*    Thi     = (float*)   (tails + KIN * 16 + KTG * 12);

    (void)hipMemsetAsync(H, 0, 2 * NBINS * 4, stream);
    (void)hipMemsetAsync(hdr, 0, 32, stream);                // hdr[4] + ctrs[4], all-zero init
    (void)hipMemsetAsync(loss, 0, 4, stream);

    unsigned n8 = n >> 3;

    hist_kernel<<<dim3(HGX, 2), 512, 0, stream>>>(input, target, H, n8);
    scan_kernel<<<2, 1024, 0, stream>>>(H, Cin);   // block 0 -> Cin, block 1 -> Ctg
    buildAB_kernel<<<NBINS / 256, 256, 0, stream>>>(Cin, Ctg, AB, hdr, n);

    matchcollect_kernel<<<dim3(MGX, 2), 1024, 0, stream>>>(input, target, AB, hdr,
                                                           in_lo_v, in_lo_i, in_hi_v, in_hi_i,
                                                           tg_lo, tg_hi, ctrs, out, bpart, n);
    loss_reduce_kernel<<<1, 1024, 0, stream>>>(bpart, loss, MGX * 16, n);
    exact_target_kernel<<<dim3((KTG + 1023) / 1024, 2), 1024, 0, stream>>>(tg_lo, tg_hi, ctrs, Tlo, Thi);
    exact_input_kernel<<<dim3((KIN + 1023) / 1024, 2), 1024, 0, stream>>>(in_lo_v, in_lo_i, in_hi_v, in_hi_i,
                                                                          ctrs, Tlo, Thi, out, loss, n);
}

// Round 12
// 468.185 us; speedup vs baseline: 1.1263x; 1.1239x over previous
//
#include <hip/hip_runtime.h>
#include <cstdint>

// HistogramLoss via coarse empirical-CDF tables (LDS histograms) + per-input-bin linear
// map (AB table) + exact tail handling in small side arrays.
// matched[i] = sorted(target)[count(input <= input[i]) - 1], loss = mean((matched-input)^2)
//
// Round-12 strategy change: 11 rounds proved the clean-loop config is pinned at ~950 GB/s
// effective (invariant under VALU/gather-location/occupancy/ILP/prefetch). So reduce BYTES:
// the target-collect full scan (64 MB) is eliminated. hist already visits every target
// element -> collect tail CANDIDATES there (fixed generous bin thresholds, per-block
// regions, LDS-allocated slots). A small filter kernel applies the exact rank thresholds;
// a fallback full-scan kernel runs ONLY if a device-side safety flag fires (threshold
// insufficient or region overflow) -> distribution-independent correctness.
// match_kernel = R9's proven-clean y=0 structure alone.

#define NBINS    8192u              // uniform bins over [-16, 16)
#define HGX      512u               // hist blocks per histogram
#define MGX      2048u              // match blocks
#define KIN      2048u              // input tail rank cutoff (per side)
#define KTG      4096u              // target tail rank cutoff (per side)
#define CLO_BIN  3328u              // candidate threshold: x <= -3.0 (tg_blo expected ~2437)
#define CHI_BIN  5120u              // candidate threshold: x >= +4.0 (tg_bhi expected ~6011)
#define CAPB     4096u              // per-hist-block candidate region capacity (per side)

__device__ __forceinline__ void bin_and_frac(float x, unsigned& b, float& frac) {
    float d = __builtin_fmaf(x, 256.0f, 4096.0f);      // (x+16)*256, one rounding, monotone
    d = fminf(fmaxf(d, 0.0f), 8191.999f);
    unsigned bb = (unsigned)d;
    b = bb;
    frac = d - (float)bb;
}

__device__ __forceinline__ void hist8c(float4 A0, float4 A1, unsigned* h, bool collect,
                                       unsigned* ccnt, float* clo, float* chi) {
    float xs[8] = {A0.x, A0.y, A0.z, A0.w, A1.x, A1.y, A1.z, A1.w};
    #pragma unroll
    for (int k = 0; k < 8; k++) {
        unsigned b; float f;
        bin_and_frac(xs[k], b, f);
        atomicAdd(&h[b], 1u);
        if (collect) {                                   // uniform branch per block
            if (b <= CLO_BIN) { unsigned p = atomicAdd(&ccnt[0], 1u); if (p < CAPB) clo[p] = xs[k]; }
            else if (b >= CHI_BIN) { unsigned p = atomicAdd(&ccnt[1], 1u); if (p < CAPB) chi[p] = xs[k]; }
        }
    }
}

// LDS-private histogram; merge non-zero bins straight into global H.
// grid (HGX, 2): y==0 -> input -> H[0:NBINS]; y==1 -> target -> H[NBINS:2*NBINS] and
// collect tail candidates into per-block regions (LDS-counter slot allocation).
__global__ __launch_bounds__(512, 8) void hist_kernel(const float* __restrict__ in,
                                                      const float* __restrict__ tg,
                                                      unsigned* __restrict__ H,
                                                      float* __restrict__ cand_lo,
                                                      float* __restrict__ cand_hi,
                                                      unsigned* __restrict__ cand_cnt,
                                                      unsigned* __restrict__ gflag,
                                                      unsigned n8) {
    __shared__ unsigned h[NBINS];
    __shared__ unsigned ccnt[2];
    for (unsigned i = threadIdx.x; i < NBINS; i += 512) h[i] = 0;
    if (threadIdx.x == 0) { ccnt[0] = 0; ccnt[1] = 0; }
    __syncthreads();
    bool collect = (blockIdx.y == 1);
    const float* xp = collect ? tg : in;
    const float4* x4 = (const float4*)xp;
    unsigned* Hh = H + blockIdx.y * NBINS;
    float* clo = cand_lo + (size_t)blockIdx.x * CAPB;
    float* chi = cand_hi + (size_t)blockIdx.x * CAPB;
    unsigned stride = gridDim.x * 512;
    unsigned i0 = blockIdx.x * 512 + threadIdx.x;
    if (i0 < n8) {
        unsigned iB = i0 + stride; unsigned iBc = (iB < n8) ? iB : i0;
        float4 p00 = x4[2 * i0], p01 = x4[2 * i0 + 1];
        float4 p10 = x4[2 * iBc], p11 = x4[2 * iBc + 1];
        for (unsigned i = i0; i < n8; i += stride) {
            unsigned nx = i + 2 * stride;
            unsigned nxc = (nx < n8) ? nx : i0;          // clamp: harmless dup load
            float4 q0 = x4[2 * nxc], q1 = x4[2 * nxc + 1];  // issue 2-ahead loads FIRST
            hist8c(p00, p01, h, collect, ccnt, clo, chi);
            p00 = p10; p01 = p11; p10 = q0; p11 = q1;    // rotate
        }
    }
    __syncthreads();
    for (unsigned i = threadIdx.x; i < NBINS; i += 512) {
        unsigned v = h[i];
        if (v) atomicAdd(&Hh[i], v);        // spread-address atomics, fire-and-forget
    }
    if (collect && threadIdx.x == 0) {
        cand_cnt[2 * blockIdx.x]     = ccnt[0];
        cand_cnt[2 * blockIdx.x + 1] = ccnt[1];
        if (ccnt[0] > CAPB || ccnt[1] > CAPB) *gflag = 1;   // idempotent store
    }
}

// Exclusive scan of one 8192-bin histogram per block -> C[NBINS+1]. grid = 2 blocks.
__global__ void scan_kernel(const unsigned* __restrict__ H, unsigned* __restrict__ C) {
    __shared__ unsigned s[1024];
    const unsigned* h = H + blockIdx.x * NBINS;
    unsigned* c = C + blockIdx.x * (NBINS + 1);
    unsigned base = threadIdx.x * 8;
    unsigned v[8]; unsigned own = 0;
    #pragma unroll
    for (int k = 0; k < 8; k++) { v[k] = h[base + k]; own += v[k]; }
    s[threadIdx.x] = own; __syncthreads();
    for (unsigned off = 1; off < 1024; off <<= 1) {
        unsigned t = (threadIdx.x >= off) ? s[threadIdx.x - off] : 0u;
        __syncthreads();
        s[threadIdx.x] += t;
        __syncthreads();
    }
    unsigned ex = s[threadIdx.x] - own;
    #pragma unroll
    for (int k = 0; k < 8; k++) { unsigned t = v[k]; c[base + k] = ex; ex += t; }
    if (threadIdx.x == 1023) c[NBINS] = s[1023];
}

// Per-input-bin linear map: matched(frac) = A[b] + B[b]*frac. Tail boundary bins for input
// (hdr[0:2]) and target (hdr[2:4]). All-zero init: bhi stored as (8192-b) under atomicMax.
__global__ void buildAB_kernel(const unsigned* __restrict__ Cin, const unsigned* __restrict__ Ctg,
                               float2* __restrict__ AB, int* __restrict__ hdr, unsigned n) {
    unsigned b = blockIdx.x * blockDim.x + threadIdx.x;
    if (b >= NBINS) return;
    unsigned r0 = Cin[b], r1 = Cin[b + 1];
    if (r1 <= KIN) atomicMax(&hdr[0], (int)b);                 // input blo
    if (r0 >= n - KIN) atomicMax(&hdr[1], (int)(8192u - b));   // input bhi (encoded)
    unsigned t0 = Ctg[b], t1 = Ctg[b + 1];
    if (t1 <= KTG) atomicMax(&hdr[2], (int)b);                 // target blo (whole-bin, rank-closed)
    if (t0 >= n - KTG) atomicMax(&hdr[3], (int)(8192u - b));   // target bhi (encoded)
    if (r1 == r0) { AB[b] = make_float2(0.f, 0.f); return; }   // empty bin, never accessed for real
    const float w = 32.0f / (float)NBINS;
    float v[2];
    unsigned rr[2] = {r0, r1};
    #pragma unroll
    for (int k = 0; k < 2; k++) {
        unsigned r = rr[k]; if (r > n - 1) r = n - 1;
        unsigned lo = 0, hi = NBINS;                            // Ctg[lo] <= r < Ctg[hi]
        while (hi - lo > 1) { unsigned mid = (lo + hi) >> 1; if (Ctg[mid] <= r) lo = mid; else hi = mid; }
        unsigned c0 = Ctg[lo], c1 = Ctg[lo + 1];
        v[k] = -16.0f + (float)lo * w + w * ((float)(r - c0 + 1) / (float)(c1 - c0));
    }
    AB[b] = make_float2(v[0], v[1] - v[0]);
}

// Filter candidates by exact rank thresholds. One block per hist-block region.
// Early-exits (fallback handles) if safety flag fired or thresholds exceed candidate bins.
__global__ __launch_bounds__(256) void filter_tg_kernel(
        const float* __restrict__ cand_lo, const float* __restrict__ cand_hi,
        const unsigned* __restrict__ cand_cnt, const unsigned* __restrict__ gflag,
        const int* __restrict__ hdr,
        float* __restrict__ tg_lo, float* __restrict__ tg_hi, unsigned* __restrict__ ctrs) {
    int blo = hdr[2], bhi = 8192 - hdr[3];
    if (*gflag || blo > (int)CLO_BIN || bhi < (int)CHI_BIN) return;
    __shared__ float buf_lo[CAPB];
    __shared__ float buf_hi[CAPB];
    __shared__ unsigned cnt2[2];
    __shared__ unsigned base2[2];
    if (threadIdx.x == 0) { cnt2[0] = 0; cnt2[1] = 0; }
    __syncthreads();
    unsigned blk = blockIdx.x;
    unsigned nlo = cand_cnt[2 * blk], nhi = cand_cnt[2 * blk + 1];
    if (nlo > CAPB) nlo = CAPB;
    if (nhi > CAPB) nhi = CAPB;
    const float* cl = cand_lo + (size_t)blk * CAPB;
    const float* ch = cand_hi + (size_t)blk * CAPB;
    for (unsigned i = threadIdx.x; i < nlo; i += 256) {
        float v = cl[i]; unsigned b; float f; bin_and_frac(v, b, f);
        if ((int)b <= blo) { unsigned p = atomicAdd(&cnt2[0], 1u); buf_lo[p] = v; }
    }
    for (unsigned i = threadIdx.x; i < nhi; i += 256) {
        float v = ch[i]; unsigned b; float f; bin_and_frac(v, b, f);
        if ((int)b >= bhi) { unsigned p = atomicAdd(&cnt2[1], 1u); buf_hi[p] = v; }
    }
    __syncthreads();
    if (threadIdx.x == 0) base2[0] = atomicAdd(&ctrs[2], cnt2[0]);   // 1 atomic/block
    if (threadIdx.x == 1) base2[1] = atomicAdd(&ctrs[3], cnt2[1]);
    __syncthreads();
    for (unsigned i = threadIdx.x; i < cnt2[0]; i += 256) tg_lo[base2[0] + i] = buf_lo[i];
    for (unsigned i = threadIdx.x; i < cnt2[1]; i += 256) tg_hi[base2[1] + i] = buf_hi[i];
}

// Fallback full target scan: runs the real work ONLY if the candidate path was unsafe.
__global__ void fallback_collect_kernel(const float* __restrict__ target,
                                        const unsigned* __restrict__ gflag,
                                        const int* __restrict__ hdr,
                                        float* __restrict__ tg_lo, float* __restrict__ tg_hi,
                                        unsigned* __restrict__ ctrs, unsigned n4) {
    int blo = hdr[2], bhi = 8192 - hdr[3];
    if (!*gflag && blo <= (int)CLO_BIN && bhi >= (int)CHI_BIN) return;   // common case
    unsigned stride = gridDim.x * blockDim.x;
    for (unsigned i = blockIdx.x * blockDim.x + threadIdx.x; i < n4; i += stride) {
        float4 v = ((const float4*)target)[i];
        float xs[4] = {v.x, v.y, v.z, v.w};
        #pragma unroll
        for (int k = 0; k < 4; k++) {
            unsigned b; float f; bin_and_frac(xs[k], b, f);
            if ((int)b <= blo) { unsigned p = atomicAdd(&ctrs[2], 1u); tg_lo[p] = xs[k]; }
            else if ((int)b >= bhi) { unsigned p = atomicAdd(&ctrs[3], 1u); tg_hi[p] = xs[k]; }
        }
    }
}

// Exact target order statistics into small arrays Tlo[r] (ranks [0,m)) and
// Thi[KTG-1-...] (top ranks). grid (4, 2): blockIdx.y = side, one j per thread.
__global__ void exact_target_kernel(const float* __restrict__ tg_lo, const float* __restrict__ tg_hi,
                                    const unsigned* __restrict__ ctrs,
                                    float* __restrict__ Tlo, float* __restrict__ Thi) {
    __shared__ __align__(16) float v[KTG];
    int side = blockIdx.y;
    const float* src = side ? tg_hi : tg_lo;
    unsigned m = ctrs[side ? 3 : 2];
    if (m > KTG) m = KTG;
    float sgn = side ? -1.f : 1.f;
    for (unsigned k = threadIdx.x; k < m; k += 1024) v[k] = sgn * src[k];
    __syncthreads();
    unsigned j = blockIdx.x * 1024 + threadIdx.x;
    if (j >= m) return;
    float y = v[j];
    unsigned lt = 0, le = 0;
    unsigned m4 = m & ~3u;
    for (unsigned k = 0; k < m4; k += 4) {
        float4 z = *(const float4*)&v[k];
        lt += (z.x < y) + (z.y < y) + (z.z < y) + (z.w < y);
        le += (z.x <= y) + (z.y <= y) + (z.z <= y) + (z.w <= y);
    }
    for (unsigned k = m4; k < m; k++) { lt += (v[k] < y); le += (v[k] <= y); }
    float yo = sgn * y;
    if (side) {
        for (unsigned idx = KTG - le; idx < KTG - lt; idx++) Thi[idx] = yo;  // global rank n-KTG+idx
    } else {
        for (unsigned r = lt; r < le; r++) Tlo[r] = yo;
    }
}

__device__ __forceinline__ float match8(float4 A0, float4 A1, unsigned i,
                                        const float2* __restrict__ AB, int blo, int bhi,
                                        float* __restrict__ out,
                                        float* __restrict__ vlo, unsigned* __restrict__ ilo,
                                        float* __restrict__ vhi, unsigned* __restrict__ ihi,
                                        unsigned* __restrict__ ctrs) {
    float xs[8] = {A0.x, A0.y, A0.z, A0.w, A1.x, A1.y, A1.z, A1.w};
    unsigned b[8]; float fr[8];
    #pragma unroll
    for (int k = 0; k < 8; k++) bin_and_frac(xs[k], b[k], fr[k]);
    float2 ab[8];
    #pragma unroll
    for (int k = 0; k < 8; k++) ab[k] = AB[b[k]];        // 8 L2 gathers in flight
    float m[8]; bool tl[8]; bool any = false; float acc = 0.f;
    #pragma unroll
    for (int k = 0; k < 8; k++) {
        m[k] = __builtin_fmaf(ab[k].y, fr[k], ab[k].x);  // tail lanes: harmless placeholder
        tl[k] = ((int)b[k] <= blo) || ((int)b[k] >= bhi);
        any = any || tl[k];
        float d = tl[k] ? 0.f : (m[k] - xs[k]);
        acc = __builtin_fmaf(d, d, acc);
    }
    ((float4*)out)[2 * i]     = make_float4(m[0], m[1], m[2], m[3]);   // covering stores
    ((float4*)out)[2 * i + 1] = make_float4(m[4], m[5], m[6], m[7]);
    if (any) {                                           // rare: tails overwritten later
        #pragma unroll
        for (int k = 0; k < 8; k++) {
            if (!tl[k]) continue;
            if ((int)b[k] <= blo) { unsigned p = atomicAdd(&ctrs[0], 1u); vlo[p] = xs[k]; ilo[p] = 8 * i + k; }
            else                  { unsigned p = atomicAdd(&ctrs[1], 1u); vhi[p] = xs[k]; ihi[p] = 8 * i + k; }
        }
    }
    return acc;
}

// Main match pass (input only now). grid (MGX), 256 threads, depth-2 prefetch rotation
// on the proven-clean addressing (32B/lane, covering float4-pair stores).
__global__ __launch_bounds__(256, 8) void match_kernel(
        const float* __restrict__ input,
        const float2* __restrict__ AB, const int* __restrict__ hdr,
        float* __restrict__ vlo, unsigned* __restrict__ ilo,
        float* __restrict__ vhi, unsigned* __restrict__ ihi,
        unsigned* __restrict__ ctrs,
        float* __restrict__ out, float* __restrict__ bpart,
        unsigned n) {
    unsigned n8 = n >> 3;
    unsigned stride = gridDim.x * 256;
    unsigned i0 = blockIdx.x * 256 + threadIdx.x;
    int blo = hdr[0], bhi = 8192 - hdr[1];
    float acc = 0.f;
    if (i0 < n8) {
        const float4* x4 = (const float4*)input;
        unsigned iB = i0 + stride; unsigned iBc = (iB < n8) ? iB : i0;
        float4 p00 = x4[2 * i0], p01 = x4[2 * i0 + 1];
        float4 p10 = x4[2 * iBc], p11 = x4[2 * iBc + 1];
        for (unsigned i = i0; i < n8; i += stride) {
            unsigned nx = i + 2 * stride;
            unsigned nxc = (nx < n8) ? nx : i0;              // clamp: harmless dup load
            float4 q0 = x4[2 * nxc], q1 = x4[2 * nxc + 1];   // issue 2-ahead loads FIRST
            acc += match8(p00, p01, i, AB, blo, bhi, out, vlo, ilo, vhi, ihi, ctrs);
            p00 = p10; p01 = p11; p10 = q0; p11 = q1;        // rotate
        }
    }
    #pragma unroll
    for (int off = 32; off > 0; off >>= 1) acc += __shfl_down(acc, off, 64);
    if ((threadIdx.x & 63) == 0)
        bpart[blockIdx.x * 4 + (threadIdx.x >> 6)] = acc;    // per-wave plain store
}

// Sum the per-wave partials -> *loss (plain store; exact_input atomicAdds after).
__global__ void loss_reduce_kernel(const float* __restrict__ bpart, float* __restrict__ loss,
                                   unsigned nb, unsigned n) {
    float s = 0.f;
    for (unsigned i = threadIdx.x; i < nb; i += 1024) s += bpart[i];
    #pragma unroll
    for (int off = 32; off > 0; off >>= 1) s += __shfl_down(s, off, 64);
    __shared__ float ws[16];
    int w = threadIdx.x >> 6;
    if ((threadIdx.x & 63) == 0) ws[w] = s;
    __syncthreads();
    if (threadIdx.x == 0) {
        float t = 0.f;
        #pragma unroll
        for (int k = 0; k < 16; k++) t += ws[k];
        *loss = t * (1.0f / (float)n);
    }
}

// Exact input tail matching. grid (2, 2): blockIdx.y = side, one j per thread.
// Runs LAST: overwrites the placeholder matched values at tail indices.
__global__ void exact_input_kernel(const float* __restrict__ in_lo_v, const unsigned* __restrict__ in_lo_i,
                                   const float* __restrict__ in_hi_v, const unsigned* __restrict__ in_hi_i,
                                   const unsigned* __restrict__ ctrs,
                                   const float* __restrict__ Tlo, const float* __restrict__ Thi,
                                   float* __restrict__ out, float* __restrict__ loss, unsigned n) {
    __shared__ __align__(16) float v[KIN];
    int side = blockIdx.y;
    const float* sv = side ? in_hi_v : in_lo_v;
    const unsigned* si = side ? in_hi_i : in_lo_i;
    unsigned m = ctrs[side ? 1 : 0];
    if (m > KIN) m = KIN;
    float sgn = side ? -1.f : 1.f;
    for (unsigned k = threadIdx.x; k < m; k += 1024) v[k] = sgn * sv[k];
    __syncthreads();
    unsigned j = blockIdx.x * 1024 + threadIdx.x;
    float d2 = 0.f;
    if (j < m) {
        float y = v[j];
        unsigned lt = 0, le = 0;
        unsigned m4 = m & ~3u;
        for (unsigned k = 0; k < m4; k += 4) {
            float4 z = *(const float4*)&v[k];
            lt += (z.x < y) + (z.y < y) + (z.z < y) + (z.w < y);
            le += (z.x <= y) + (z.y <= y) + (z.z <= y) + (z.w <= y);
        }
        for (unsigned k = m4; k < m; k++) { lt += (v[k] < y); le += (v[k] <= y); }
        // bottom: global rank = le-1 (< KIN <= KTG). top: global rank = n-1-lt -> Thi[KTG-1-lt].
        float mv = side ? Thi[KTG - 1 - lt] : Tlo[le - 1];
        float x = sgn * y;
        out[si[j]] = mv;
        float d = mv - x;
        d2 = d * d;
    }
    #pragma unroll
    for (int off = 32; off > 0; off >>= 1) d2 += __shfl_down(d2, off, 64);
    if ((threadIdx.x & 63) == 0 && d2 != 0.f)
        atomicAdd(loss, d2 * (1.0f / (float)n));
}

extern "C" void kernel_launch(void* const* d_in, const int* in_sizes, int n_in,
                              void* d_out, int out_size, void* d_ws, size_t ws_size,
                              hipStream_t stream) {
    const float* input  = (const float*)d_in[0];
    const float* target = (const float*)d_in[1];
    unsigned n = (unsigned)in_sizes[0];   // 16777216 = 2^24
    float* out  = (float*)d_out;
    float* loss = out + n;

    char* wsb = (char*)d_ws;
    unsigned* H    = (unsigned*)(wsb);                       // 2*NBINS*4 = 64 KB
    unsigned* Cin  = (unsigned*)(wsb + 64 * 1024);           // 2*(NBINS+1)*4
    unsigned* Ctg  = Cin + (NBINS + 1);
    float2*   AB   = (float2*)  (wsb + 160 * 1024);          // 64 KB
    char*     aux  = wsb + 224 * 1024;
    int*      hdr  = (int*)     (aux);                       // 16B [in_blo, enc_in_bhi, tg_blo, enc_tg_bhi]
    unsigned* ctrs = (unsigned*)(aux + 16);                  // 16B [in_lo, in_hi, tg_lo, tg_hi]
    unsigned* gflag= (unsigned*)(aux + 32);                  // 4B safety flag
    float*    bpart= (float*)   (aux + 64);                  // MGX*4 floats (32 KB)
    char*     tails= aux + 64 + 65536 + 64;
    float*    in_lo_v = (float*)   (tails);
    unsigned* in_lo_i = (unsigned*)(tails + KIN * 4);
    float*    in_hi_v = (float*)   (tails + KIN * 8);
    unsigned* in_hi_i = (unsigned*)(tails + KIN * 12);
    float*    tg_lo   = (float*)   (tails + KIN * 16);
    float*    tg_hi   = (float*)   (tails + KIN * 16 + KTG * 4);
    float*    Tlo     = (float*)   (tails + KIN * 16 + KTG * 8);
    float*    Thi     = (float*)   (tails + KIN * 16 + KTG * 12);
    unsigned* cand_cnt= (unsigned*)(wsb + 512 * 1024);       // 2*HGX u32
    float*    cand_lo = (float*)   (wsb + 1024 * 1024);      // HGX*CAPB floats (8 MB)
    float*    cand_hi = (float*)   (wsb + 10 * 1024 * 1024); // HGX*CAPB floats (8 MB)

    (void)hipMemsetAsync(H, 0, 2 * NBINS * 4, stream);
    (void)hipMemsetAsync(hdr, 0, 48, stream);                // hdr + ctrs + gflag, all-zero init
    (void)hipMemsetAsync(loss, 0, 4, stream);

    unsigned n8 = n >> 3;
    unsigned n4 = n >> 2;

    hist_kernel<<<dim3(HGX, 2), 512, 0, stream>>>(input, target, H, cand_lo, cand_hi,
                                                  cand_cnt, gflag, n8);
    scan_kernel<<<2, 1024, 0, stream>>>(H, Cin);   // block 0 -> Cin, block 1 -> Ctg
    buildAB_kernel<<<NBINS / 256, 256, 0, stream>>>(Cin, Ctg, AB, hdr, n);

    filter_tg_kernel<<<HGX, 256, 0, stream>>>(cand_lo, cand_hi, cand_cnt, gflag, hdr,
                                              tg_lo, tg_hi, ctrs);
    fallback_collect_kernel<<<2048, 256, 0, stream>>>(target, gflag, hdr, tg_lo, tg_hi, ctrs, n4);

    match_kernel<<<MGX, 256, 0, stream>>>(input, AB, hdr, in_lo_v, in_lo_i, in_hi_v, in_hi_i,
                                          ctrs, out, bpart, n);
    loss_reduce_kernel<<<1, 1024, 0, stream>>>(bpart, loss, MGX * 4, n);
    exact_target_kernel<<<dim3((KTG + 1023) / 1024, 2), 1024, 0, stream>>>(tg_lo, tg_hi, ctrs, Tlo, Thi);
    exact_input_kernel<<<dim3((KIN + 1023) / 1024, 2), 1024, 0, stream>>>(in_lo_v, in_lo_i, in_hi_v, in_hi_i,
                                                                          ctrs, Tlo, Thi, out, loss, n);
}